// Round 1
// baseline (468.709 us; speedup 1.0000x reference)
//
#include <hip/hip_runtime.h>

// ---------------------------------------------------------------------------
// AttentionThinkingBlock: LN1 -> QKV -> causal attn -> proj+res -> LN2 -> MLP
// B=2, S=2048, D=1024, H=16, HS=64.  All internal matmuls in bf16 MFMA.
// ---------------------------------------------------------------------------

typedef __bf16 bf16_t;
typedef __attribute__((ext_vector_type(8))) __bf16 bf16x8;
typedef __attribute__((ext_vector_type(4))) __bf16 bf16x4;
typedef __attribute__((ext_vector_type(4))) float f32x4;

__device__ __forceinline__ f32x4 mfma16(bf16x8 a, bf16x8 b, f32x4 c) {
  return __builtin_amdgcn_mfma_f32_16x16x32_bf16(a, b, c, 0, 0, 0);
}

// async global->LDS, 16B per lane; LDS dest must be wave-uniform base (+lane*16 by HW)
__device__ __forceinline__ void gll16(const void* g, void* l) {
  __builtin_amdgcn_global_load_lds(
      (const __attribute__((address_space(1))) void*)g,
      (__attribute__((address_space(3))) void*)l, 16, 0, 0);
}

// ---------------------------------------------------------------------------
// LayerNorm (f32 in) -> bf16 out.  One block per row, D=1024, 256 thr x 4 elems.
// ---------------------------------------------------------------------------
__global__ __launch_bounds__(256) void ln_kernel(
    const float* __restrict__ x, const float* __restrict__ g,
    const float* __restrict__ be, bf16_t* __restrict__ out) {
  const int row = blockIdx.x;
  const int tid = threadIdx.x;
  const float4 v = *(reinterpret_cast<const float4*>(x + (size_t)row * 1024) + tid);
  float s1 = v.x + v.y + v.z + v.w;
  float s2 = v.x * v.x + v.y * v.y + v.z * v.z + v.w * v.w;
#pragma unroll
  for (int off = 1; off < 64; off <<= 1) {
    s1 += __shfl_xor(s1, off);
    s2 += __shfl_xor(s2, off);
  }
  __shared__ float red[8];
  const int l = tid & 63, w = tid >> 6;
  if (l == 0) { red[w] = s1; red[w + 4] = s2; }
  __syncthreads();
  s1 = red[0] + red[1] + red[2] + red[3];
  s2 = red[4] + red[5] + red[6] + red[7];
  const float mu = s1 * (1.f / 1024.f);
  const float var = s2 * (1.f / 1024.f) - mu * mu;
  const float rstd = rsqrtf(var + 1e-5f);
  const float4 gg = *(reinterpret_cast<const float4*>(g) + tid);
  const float4 bb = *(reinterpret_cast<const float4*>(be) + tid);
  bf16x4 o;
  o[0] = (bf16_t)((v.x - mu) * rstd * gg.x + bb.x);
  o[1] = (bf16_t)((v.y - mu) * rstd * gg.y + bb.y);
  o[2] = (bf16_t)((v.z - mu) * rstd * gg.z + bb.z);
  o[3] = (bf16_t)((v.w - mu) * rstd * gg.w + bb.w);
  *(reinterpret_cast<bf16x4*>(out + (size_t)row * 1024) + tid) = o;
}

// ---------------------------------------------------------------------------
// Batched transpose+convert: in f32 [bz][R][C] -> out bf16 [bz][C][R]
// 32x32 tiles, block (32,8).
// ---------------------------------------------------------------------------
__global__ __launch_bounds__(256) void transpose_cvt(
    const float* __restrict__ in, bf16_t* __restrict__ out, int R, int C) {
  __shared__ float t[32][33];
  const int bz = blockIdx.z;
  in += (size_t)bz * R * C;
  out += (size_t)bz * R * C;
  const int c0 = blockIdx.x * 32, r0 = blockIdx.y * 32;
  const int tx = threadIdx.x, ty = threadIdx.y;
#pragma unroll
  for (int i = 0; i < 4; i++)
    t[ty + i * 8][tx] = in[(size_t)(r0 + ty + i * 8) * C + c0 + tx];
  __syncthreads();
#pragma unroll
  for (int i = 0; i < 4; i++)
    out[(size_t)(c0 + ty + i * 8) * R + r0 + tx] = (bf16_t)t[tx][ty + i * 8];
}

// ---------------------------------------------------------------------------
// GEMM C[M,N] = A[M,K] @ B^T[N,K]   (m97 structure: 128x128 tile, BK=32,
// 4 waves 2x2, global_load_lds w16, linear LDS, 16x16x32 bf16 MFMA)
// MODE 0 = QKV epilogue (q/k -> qkbuf bf16 [t][2048], v -> vT bf16 [b*1024+n][2048])
// MODE 1 = f32 out = acc + bias[c] + resid   (proj -> h, ff2 -> d_out)
// MODE 2 = bf16 out = relu(acc + bias[c])    (ff1)
// ---------------------------------------------------------------------------
template <int MODE>
__global__ __launch_bounds__(256) void gemm_bt(
    const bf16_t* __restrict__ A, const bf16_t* __restrict__ BT,
    const float* __restrict__ bias, const float* __restrict__ resid,
    void* __restrict__ out0, void* __restrict__ out1, int M, int N, int K) {
  __shared__ __align__(16) bf16_t Al[128 * 32];
  __shared__ __align__(16) bf16_t Bl[128 * 32];
  const int tid = threadIdx.x;
  const int l = tid & 63, w = tid >> 6;
  const int wr = w >> 1, wc = w & 1;
  const int lr = l & 15, lg = l >> 4;
  const int bm = blockIdx.y * 128, bn = blockIdx.x * 128;

  f32x4 acc[4][4];
#pragma unroll
  for (int i = 0; i < 4; i++)
#pragma unroll
    for (int j = 0; j < 4; j++) acc[i][j] = (f32x4)(0.f);

  const char* Ag = (const char*)(A + (size_t)bm * K);
  const char* Bg = (const char*)(BT + (size_t)bn * K);
  const size_t rowb = (size_t)K * 2;  // row stride bytes
  const int nK = K >> 5;

  for (int kt = 0; kt < nK; ++kt) {
    // ---- stage 128x32 bf16 tiles of A and B^T (linear LDS). slot = i*256+tid,
    // row = slot/4, 16B chunk = slot%4.
#pragma unroll
    for (int i = 0; i < 2; i++) {
      const int s = i * 256 + tid;
      const size_t go = (size_t)(s >> 2) * rowb + (size_t)(kt * 64 + (s & 3) * 16);
      gll16(Ag + go, (char*)Al + (i * 256 + w * 64) * 16);
      gll16(Bg + go, (char*)Bl + (i * 256 + w * 64) * 16);
    }
    __syncthreads();
    // ---- fragments: A row = wr*64+mi*16+lr, k = lg*8..+8 ; B col likewise
    bf16x8 af[4], bfr[4];
#pragma unroll
    for (int mi = 0; mi < 4; mi++)
      af[mi] = *reinterpret_cast<const bf16x8*>(Al + (wr * 64 + mi * 16 + lr) * 32 + lg * 8);
#pragma unroll
    for (int ni = 0; ni < 4; ni++)
      bfr[ni] = *reinterpret_cast<const bf16x8*>(Bl + (wc * 64 + ni * 16 + lr) * 32 + lg * 8);
#pragma unroll
    for (int mi = 0; mi < 4; mi++)
#pragma unroll
      for (int ni = 0; ni < 4; ni++)
        acc[mi][ni] = mfma16(af[mi], bfr[ni], acc[mi][ni]);
    __syncthreads();
  }

  // ---- epilogue. C layout: row = (l>>4)*4+j, col = l&15  (m89-verified)
#pragma unroll
  for (int mi = 0; mi < 4; mi++) {
    const int r = bm + wr * 64 + mi * 16 + lg * 4;
#pragma unroll
    for (int ni = 0; ni < 4; ni++) {
      const int c = bn + wc * 64 + ni * 16 + lr;
      f32x4 v = acc[mi][ni];
      if constexpr (MODE == 1) {
        const float bb = bias[c];
        float* o = (float*)out0;
#pragma unroll
        for (int j = 0; j < 4; j++)
          o[(size_t)(r + j) * N + c] = v[j] + bb + resid[(size_t)(r + j) * N + c];
      } else if constexpr (MODE == 2) {
        const float bb = bias[c];
        bf16_t* o = (bf16_t*)out0;
#pragma unroll
        for (int j = 0; j < 4; j++)
          o[(size_t)(r + j) * N + c] = (bf16_t)fmaxf(v[j] + bb, 0.f);
      } else {  // QKV: cols [0,2048) -> qk buffer; [2048,3072) -> vT transposed
        if (c < 2048) {
          bf16_t* o = (bf16_t*)out0;
#pragma unroll
          for (int j = 0; j < 4; j++)
            o[(size_t)(r + j) * 2048 + c] = (bf16_t)v[j];
        } else {
          const int nn = c - 2048;          // h*64+hs
          const int bI = r >> 11, tl = r & 2047;
          bf16x4 pk;
#pragma unroll
          for (int j = 0; j < 4; j++) pk[j] = (bf16_t)v[j];
          *reinterpret_cast<bf16x4*>((bf16_t*)out1 +
              ((size_t)(bI * 1024 + nn)) * 2048 + tl) = pk;
        }
      }
    }
  }
}

// ---------------------------------------------------------------------------
// Causal flash attention.  grid=(qt=32, bh=32), block=256 (4 waves x 16 Q rows).
// qk: bf16 [4096][2048] (cols 0-1023=q, 1024-2047=k, head-major inside).
// vT: bf16 [32*64][2048]  (V transposed: [b*16+h][hs][t]).
// ac: bf16 [4096][1024]   concat-head output (A operand of proj GEMM).
// ---------------------------------------------------------------------------
__global__ __launch_bounds__(256) void attn_kernel(
    const bf16_t* __restrict__ qk, const bf16_t* __restrict__ vT,
    bf16_t* __restrict__ ac) {
  const int qt = blockIdx.x;
  const int bh = blockIdx.y;
  const int b = bh >> 4, h = bh & 15;
  const int tid = threadIdx.x;
  const int l = tid & 63, w = tid >> 6;
  const int lr = l & 15, lg = l >> 4;

  __shared__ __align__(16) bf16_t kl[64 * 72];      // K tile [s][hs], pad 8
  __shared__ __align__(16) bf16_t vl[64 * 72];      // V^T tile [hs][s], pad 8
  __shared__ __align__(16) bf16_t pl[4][16 * 72];   // per-wave P re-layout

  // Q fragments hoisted: A-operand, row=lr, k=kc*32+lg*8..+8
  const bf16_t* qp = qk + ((size_t)(b * 2048 + qt * 64 + w * 16 + lr)) * 2048 + h * 64;
  bf16x8 qf[2];
  qf[0] = *reinterpret_cast<const bf16x8*>(qp + lg * 8);
  qf[1] = *reinterpret_cast<const bf16x8*>(qp + 32 + lg * 8);

  f32x4 oacc[4];
#pragma unroll
  for (int i = 0; i < 4; i++) oacc[i] = (f32x4)(0.f);
  float mrow[4], lrow[4];
#pragma unroll
  for (int j = 0; j < 4; j++) { mrow[j] = -1e30f; lrow[j] = 0.f; }
  const int rbase = qt * 64 + w * 16 + lg * 4;

  for (int st = 0; st <= qt; ++st) {
    __syncthreads();  // prev-tile LDS reads complete before overwrite
#pragma unroll
    for (int i = 0; i < 2; i++) {  // stage K and V^T tiles (coalesced 16B)
      const int ch = tid + i * 256;
      const int r = ch >> 3, c = (ch & 7) * 8;
      *reinterpret_cast<bf16x8*>(&kl[r * 72 + c]) =
          *reinterpret_cast<const bf16x8*>(
              qk + ((size_t)(b * 2048 + st * 64 + r)) * 2048 + 1024 + h * 64 + c);
      *reinterpret_cast<bf16x8*>(&vl[r * 72 + c]) =
          *reinterpret_cast<const bf16x8*>(
              vT + ((size_t)(bh * 64 + r)) * 2048 + st * 64 + c);
    }
    __syncthreads();

    // S = Q K^T : 4 col-tiles x (K=64 -> 2 mfma)
    f32x4 sc4[4];
#pragma unroll
    for (int ct = 0; ct < 4; ct++) sc4[ct] = (f32x4)(0.f);
#pragma unroll
    for (int ct = 0; ct < 4; ct++)
#pragma unroll
      for (int kc = 0; kc < 2; kc++) {
        bf16x8 kf = *reinterpret_cast<const bf16x8*>(
            &kl[(ct * 16 + lr) * 72 + kc * 32 + lg * 8]);
        sc4[ct] = mfma16(qf[kc], kf, sc4[ct]);
      }

    // scale + causal mask (diagonal tile only)
#pragma unroll
    for (int ct = 0; ct < 4; ct++)
#pragma unroll
      for (int j = 0; j < 4; j++) {
        float sv = sc4[ct][j] * 0.125f;
        if (st == qt) {
          const int col = st * 64 + ct * 16 + lr;
          if (col > rbase + j) sv = -1e30f;
        }
        sc4[ct][j] = sv;
      }

    // online softmax (rows live in reg j across 16 lanes of same lg-group)
    float rmax[4];
#pragma unroll
    for (int j = 0; j < 4; j++)
      rmax[j] = fmaxf(fmaxf(sc4[0][j], sc4[1][j]), fmaxf(sc4[2][j], sc4[3][j]));
#pragma unroll
    for (int off = 1; off < 16; off <<= 1)
#pragma unroll
      for (int j = 0; j < 4; j++) rmax[j] = fmaxf(rmax[j], __shfl_xor(rmax[j], off));
    float fac[4];
#pragma unroll
    for (int j = 0; j < 4; j++) {
      const float mn = fmaxf(mrow[j], rmax[j]);
      fac[j] = __expf(mrow[j] - mn);
      mrow[j] = mn;
    }
    float rsum[4] = {0.f, 0.f, 0.f, 0.f};
#pragma unroll
    for (int ct = 0; ct < 4; ct++)
#pragma unroll
      for (int j = 0; j < 4; j++) {
        const float p = __expf(sc4[ct][j] - mrow[j]);
        sc4[ct][j] = p;
        rsum[j] += p;
      }
#pragma unroll
    for (int off = 1; off < 16; off <<= 1)
#pragma unroll
      for (int j = 0; j < 4; j++) rsum[j] += __shfl_xor(rsum[j], off);
#pragma unroll
    for (int j = 0; j < 4; j++) lrow[j] = lrow[j] * fac[j] + rsum[j];
#pragma unroll
    for (int ht = 0; ht < 4; ht++)
#pragma unroll
      for (int j = 0; j < 4; j++) oacc[ht][j] *= fac[j];

    // P: C-layout -> A-fragment layout via per-wave LDS (no barrier: same wave)
#pragma unroll
    for (int ct = 0; ct < 4; ct++)
#pragma unroll
      for (int j = 0; j < 4; j++)
        pl[w][(lg * 4 + j) * 72 + ct * 16 + lr] = (bf16_t)sc4[ct][j];
    bf16x8 pf[2];
#pragma unroll
    for (int sc = 0; sc < 2; sc++)
      pf[sc] = *reinterpret_cast<const bf16x8*>(&pl[w][lr * 72 + sc * 32 + lg * 8]);

    // O += P @ V : 4 hs-tiles x 2 s-chunks
#pragma unroll
    for (int ht = 0; ht < 4; ht++)
#pragma unroll
      for (int sc = 0; sc < 2; sc++) {
        bf16x8 vf = *reinterpret_cast<const bf16x8*>(
            &vl[(ht * 16 + lr) * 72 + sc * 32 + lg * 8]);
        oacc[ht] = mfma16(pf[sc], vf, oacc[ht]);
      }
  }

  // epilogue: O/l -> concat-head layout [t][h*64+hs]
#pragma unroll
  for (int ht = 0; ht < 4; ht++)
#pragma unroll
    for (int j = 0; j < 4; j++) {
      const size_t t = (size_t)(b * 2048 + qt * 64 + w * 16 + lg * 4 + j);
      ac[t * 1024 + h * 64 + ht * 16 + lr] = (bf16_t)(oacc[ht][j] / lrow[j]);
    }
}

// ---------------------------------------------------------------------------
extern "C" void kernel_launch(void* const* d_in, const int* in_sizes, int n_in,
                              void* d_out, int out_size, void* d_ws, size_t ws_size,
                              hipStream_t stream) {
  const float* x     = (const float*)d_in[0];
  const float* wq    = (const float*)d_in[1];
  const float* wk    = (const float*)d_in[2];
  const float* wv    = (const float*)d_in[3];
  const float* wproj = (const float*)d_in[4];
  const float* bproj = (const float*)d_in[5];
  const float* w1    = (const float*)d_in[6];
  const float* b1    = (const float*)d_in[7];
  const float* w2    = (const float*)d_in[8];
  const float* b2    = (const float*)d_in[9];
  const float* ln1g  = (const float*)d_in[10];
  const float* ln1b  = (const float*)d_in[11];
  const float* ln2g  = (const float*)d_in[12];
  const float* ln2b  = (const float*)d_in[13];
  float* out = (float*)d_out;

  char* ws = (char*)d_ws;
  const size_t MB = 1 << 20;
  bf16_t* xn  = (bf16_t*)(ws + 0);         // 8 MB   (reused as hn after LN2)
  bf16_t* wT  = (bf16_t*)(ws + 8 * MB);    // 8 MB   weight-transpose slot
  float*  hbuf= (float*)(ws + 16 * MB);    // 16 MB  residual h (f32)
  bf16_t* qkb = (bf16_t*)(ws + 32 * MB);   // 16 MB  q|k  [4096][2048]
  bf16_t* vTb = (bf16_t*)(ws + 48 * MB);   // 8 MB   v^T  [2048][2048]
  bf16_t* acb = (bf16_t*)(ws + 56 * MB);   // 8 MB   attn concat
  bf16_t* ffa = (bf16_t*)(ws + 32 * MB);   // 32 MB  ff1 act (reuses qk/vT region)
  bf16_t* hn  = xn;

  dim3 tb(32, 8);

  // LN1
  ln_kernel<<<4096, 256, 0, stream>>>(x, ln1g, ln1b, xn);
  // W_qkv^T : per-head transpose [1024][64] -> rows h*64+hs
  transpose_cvt<<<dim3(2, 32, 16), tb, 0, stream>>>(wq, wT, 1024, 64);
  transpose_cvt<<<dim3(2, 32, 16), tb, 0, stream>>>(wk, wT + 1024 * 1024, 1024, 64);
  transpose_cvt<<<dim3(2, 32, 16), tb, 0, stream>>>(wv, wT + 2048 * 1024, 1024, 64);
  // QKV GEMM: [4096,1024] x [3072,1024]^T
  gemm_bt<0><<<dim3(24, 32), 256, 0, stream>>>(xn, wT, nullptr, nullptr, qkb, vTb,
                                               4096, 3072, 1024);
  // attention
  attn_kernel<<<dim3(32, 32), 256, 0, stream>>>(qkb, vTb, acb);
  // proj: +bproj +x -> h (f32)
  transpose_cvt<<<dim3(32, 32, 1), tb, 0, stream>>>(wproj, wT, 1024, 1024);
  gemm_bt<1><<<dim3(8, 32), 256, 0, stream>>>(acb, wT, bproj, x, hbuf, nullptr,
                                              4096, 1024, 1024);
  // LN2
  ln_kernel<<<4096, 256, 0, stream>>>(hbuf, ln2g, ln2b, hn);
  // FF1: relu(hn@w1+b1) -> bf16
  transpose_cvt<<<dim3(128, 32, 1), tb, 0, stream>>>(w1, wT, 1024, 4096);
  gemm_bt<2><<<dim3(32, 32), 256, 0, stream>>>(hn, wT, b1, nullptr, ffa, nullptr,
                                               4096, 4096, 1024);
  // FF2: ffa@w2+b2+h -> out (f32)
  transpose_cvt<<<dim3(32, 128, 1), tb, 0, stream>>>(w2, wT, 4096, 1024);
  gemm_bt<1><<<dim3(8, 32), 256, 0, stream>>>(ffa, wT, b2, hbuf, out, nullptr,
                                              4096, 1024, 4096);
}

// Round 3
// 425.885 us; speedup vs baseline: 1.1006x; 1.1006x over previous
//
#include <hip/hip_runtime.h>

// ---------------------------------------------------------------------------
// AttentionThinkingBlock: LN1 -> QKV -> causal attn -> proj+res -> LN2 -> MLP
// B=2, S=2048, D=1024, H=16, HS=64.  All internal matmuls in bf16 MFMA.
// ---------------------------------------------------------------------------

typedef __bf16 bf16_t;
typedef __attribute__((ext_vector_type(8))) __bf16 bf16x8;
typedef __attribute__((ext_vector_type(4))) __bf16 bf16x4;
typedef __attribute__((ext_vector_type(4))) float f32x4;

__device__ __forceinline__ f32x4 mfma16(bf16x8 a, bf16x8 b, f32x4 c) {
  return __builtin_amdgcn_mfma_f32_16x16x32_bf16(a, b, c, 0, 0, 0);
}

// async global->LDS, 16B per lane; LDS dest must be wave-uniform base (+lane*16 by HW)
__device__ __forceinline__ void gll16(const void* g, void* l) {
  __builtin_amdgcn_global_load_lds(
      (const __attribute__((address_space(1))) void*)g,
      (__attribute__((address_space(3))) void*)l, 16, 0, 0);
}

// ---------------------------------------------------------------------------
// LayerNorm (f32 in) -> bf16 out.  One block per row, D=1024, 256 thr x 4 elems.
// ---------------------------------------------------------------------------
__global__ __launch_bounds__(256) void ln_kernel(
    const float* __restrict__ x, const float* __restrict__ g,
    const float* __restrict__ be, bf16_t* __restrict__ out) {
  const int row = blockIdx.x;
  const int tid = threadIdx.x;
  const float4 v = *(reinterpret_cast<const float4*>(x + (size_t)row * 1024) + tid);
  float s1 = v.x + v.y + v.z + v.w;
  float s2 = v.x * v.x + v.y * v.y + v.z * v.z + v.w * v.w;
#pragma unroll
  for (int off = 1; off < 64; off <<= 1) {
    s1 += __shfl_xor(s1, off);
    s2 += __shfl_xor(s2, off);
  }
  __shared__ float red[8];
  const int l = tid & 63, w = tid >> 6;
  if (l == 0) { red[w] = s1; red[w + 4] = s2; }
  __syncthreads();
  s1 = red[0] + red[1] + red[2] + red[3];
  s2 = red[4] + red[5] + red[6] + red[7];
  const float mu = s1 * (1.f / 1024.f);
  const float var = s2 * (1.f / 1024.f) - mu * mu;
  const float rstd = rsqrtf(var + 1e-5f);
  const float4 gg = *(reinterpret_cast<const float4*>(g) + tid);
  const float4 bb = *(reinterpret_cast<const float4*>(be) + tid);
  bf16x4 o;
  o[0] = (bf16_t)((v.x - mu) * rstd * gg.x + bb.x);
  o[1] = (bf16_t)((v.y - mu) * rstd * gg.y + bb.y);
  o[2] = (bf16_t)((v.z - mu) * rstd * gg.z + bb.z);
  o[3] = (bf16_t)((v.w - mu) * rstd * gg.w + bb.w);
  *(reinterpret_cast<bf16x4*>(out + (size_t)row * 1024) + tid) = o;
}

// ---------------------------------------------------------------------------
// Batched transpose+convert: in f32 [bz][R][C] -> out bf16 [bz][C][R]
// ---------------------------------------------------------------------------
__global__ __launch_bounds__(256) void transpose_cvt(
    const float* __restrict__ in, bf16_t* __restrict__ out, int R, int C) {
  __shared__ float t[32][33];
  const int bz = blockIdx.z;
  in += (size_t)bz * R * C;
  out += (size_t)bz * R * C;
  const int c0 = blockIdx.x * 32, r0 = blockIdx.y * 32;
  const int tx = threadIdx.x, ty = threadIdx.y;
#pragma unroll
  for (int i = 0; i < 4; i++)
    t[ty + i * 8][tx] = in[(size_t)(r0 + ty + i * 8) * C + c0 + tx];
  __syncthreads();
#pragma unroll
  for (int i = 0; i < 4; i++)
    out[(size_t)(c0 + ty + i * 8) * R + r0 + tx] = (bf16_t)t[tx][ty + i * 8];
}

// ---------------------------------------------------------------------------
// GEMM C[M,N] = A[M,K] @ B^T[N,K]  (m97 structure + XCD-aware block swizzle)
// MODE 0 = QKV epilogue  MODE 1 = f32 out = acc+bias+resid  MODE 2 = relu bf16
// ---------------------------------------------------------------------------
template <int MODE>
__global__ __launch_bounds__(256) void gemm_bt(
    const bf16_t* __restrict__ A, const bf16_t* __restrict__ BT,
    const float* __restrict__ bias, const float* __restrict__ resid,
    void* __restrict__ out0, void* __restrict__ out1, int M, int N, int K) {
  __shared__ __align__(16) bf16_t Al[128 * 32];
  __shared__ __align__(16) bf16_t Bl[128 * 32];
  const int tid = threadIdx.x;
  const int l = tid & 63, w = tid >> 6;
  const int wr = w >> 1, wc = w & 1;
  const int lr = l & 15, lg = l >> 4;
  // XCD-aware swizzle (nwg % 8 == 0 for every launch below)
  const int gx = gridDim.x;
  const int nwg = gx * gridDim.y;
  int flat = blockIdx.y * gx + blockIdx.x;
  flat = (flat & 7) * (nwg >> 3) + (flat >> 3);
  const int bm = (flat / gx) * 128, bn = (flat % gx) * 128;

  f32x4 acc[4][4];
#pragma unroll
  for (int i = 0; i < 4; i++)
#pragma unroll
    for (int j = 0; j < 4; j++) acc[i][j] = (f32x4)(0.f);

  const char* Ag = (const char*)(A + (size_t)bm * K);
  const char* Bg = (const char*)(BT + (size_t)bn * K);
  const size_t rowb = (size_t)K * 2;
  const int nK = K >> 5;

  for (int kt = 0; kt < nK; ++kt) {
#pragma unroll
    for (int i = 0; i < 2; i++) {
      const int s = i * 256 + tid;
      const size_t go = (size_t)(s >> 2) * rowb + (size_t)(kt * 64 + (s & 3) * 16);
      gll16(Ag + go, (char*)Al + (i * 256 + w * 64) * 16);
      gll16(Bg + go, (char*)Bl + (i * 256 + w * 64) * 16);
    }
    __syncthreads();
    bf16x8 af[4], bfr[4];
#pragma unroll
    for (int mi = 0; mi < 4; mi++)
      af[mi] = *reinterpret_cast<const bf16x8*>(Al + (wr * 64 + mi * 16 + lr) * 32 + lg * 8);
#pragma unroll
    for (int ni = 0; ni < 4; ni++)
      bfr[ni] = *reinterpret_cast<const bf16x8*>(Bl + (wc * 64 + ni * 16 + lr) * 32 + lg * 8);
#pragma unroll
    for (int mi = 0; mi < 4; mi++)
#pragma unroll
      for (int ni = 0; ni < 4; ni++)
        acc[mi][ni] = mfma16(af[mi], bfr[ni], acc[mi][ni]);
    __syncthreads();
  }

#pragma unroll
  for (int mi = 0; mi < 4; mi++) {
    const int r = bm + wr * 64 + mi * 16 + lg * 4;
#pragma unroll
    for (int ni = 0; ni < 4; ni++) {
      const int c = bn + wc * 64 + ni * 16 + lr;
      f32x4 v = acc[mi][ni];
      if constexpr (MODE == 1) {
        const float bb = bias[c];
        float* o = (float*)out0;
#pragma unroll
        for (int j = 0; j < 4; j++)
          o[(size_t)(r + j) * N + c] = v[j] + bb + resid[(size_t)(r + j) * N + c];
      } else if constexpr (MODE == 2) {
        const float bb = bias[c];
        bf16_t* o = (bf16_t*)out0;
#pragma unroll
        for (int j = 0; j < 4; j++)
          o[(size_t)(r + j) * N + c] = (bf16_t)fmaxf(v[j] + bb, 0.f);
      } else {
        if (c < 2048) {
          bf16_t* o = (bf16_t*)out0;
#pragma unroll
          for (int j = 0; j < 4; j++)
            o[(size_t)(r + j) * 2048 + c] = (bf16_t)v[j];
        } else {
          const int nn = c - 2048;
          const int bI = r >> 11, tl = r & 2047;
          bf16x4 pk;
#pragma unroll
          for (int j = 0; j < 4; j++) pk[j] = (bf16_t)v[j];
          *reinterpret_cast<bf16x4*>((bf16_t*)out1 +
              ((size_t)(bI * 1024 + nn)) * 2048 + tl) = pk;
        }
      }
    }
  }
}

// ---------------------------------------------------------------------------
// One K-tile of flash attention for one wave's 16 Q-rows.
// kl/vl: staged 64x64 tiles (stride 72).  plw: per-wave P relayout buffer.
// ---------------------------------------------------------------------------
__device__ __forceinline__ void attn_tile(
    const bf16_t* __restrict__ kl, const bf16_t* __restrict__ vl,
    bf16_t* __restrict__ plw, const bf16x8* qf, f32x4* oacc,
    float* mrow, float* lrow, const int lr, const int lg,
    const int rbase, const int cbase, const bool diag) {
  f32x4 sc4[4];
#pragma unroll
  for (int ct = 0; ct < 4; ct++) sc4[ct] = (f32x4)(0.f);
#pragma unroll
  for (int ct = 0; ct < 4; ct++)
#pragma unroll
    for (int kc = 0; kc < 2; kc++) {
      bf16x8 kf = *reinterpret_cast<const bf16x8*>(
          &kl[(ct * 16 + lr) * 72 + kc * 32 + lg * 8]);
      sc4[ct] = mfma16(qf[kc], kf, sc4[ct]);
    }
#pragma unroll
  for (int ct = 0; ct < 4; ct++)
#pragma unroll
    for (int j = 0; j < 4; j++) {
      float sv = sc4[ct][j] * 0.125f;
      if (diag && (cbase + ct * 16 + lr > rbase + j)) sv = -1e30f;
      sc4[ct][j] = sv;
    }
  float rmax[4];
#pragma unroll
  for (int j = 0; j < 4; j++)
    rmax[j] = fmaxf(fmaxf(sc4[0][j], sc4[1][j]), fmaxf(sc4[2][j], sc4[3][j]));
#pragma unroll
  for (int off = 1; off < 16; off <<= 1)
#pragma unroll
    for (int j = 0; j < 4; j++) rmax[j] = fmaxf(rmax[j], __shfl_xor(rmax[j], off));
  float fac[4];
#pragma unroll
  for (int j = 0; j < 4; j++) {
    const float mn = fmaxf(mrow[j], rmax[j]);
    fac[j] = __expf(mrow[j] - mn);
    mrow[j] = mn;
  }
  float rsum[4] = {0.f, 0.f, 0.f, 0.f};
#pragma unroll
  for (int ct = 0; ct < 4; ct++)
#pragma unroll
    for (int j = 0; j < 4; j++) {
      const float pv = __expf(sc4[ct][j] - mrow[j]);
      sc4[ct][j] = pv;
      rsum[j] += pv;
    }
#pragma unroll
  for (int off = 1; off < 16; off <<= 1)
#pragma unroll
    for (int j = 0; j < 4; j++) rsum[j] += __shfl_xor(rsum[j], off);
#pragma unroll
  for (int j = 0; j < 4; j++) lrow[j] = lrow[j] * fac[j] + rsum[j];
#pragma unroll
  for (int ht = 0; ht < 4; ht++)
#pragma unroll
    for (int j = 0; j < 4; j++) oacc[ht][j] *= fac[j];
#pragma unroll
  for (int ct = 0; ct < 4; ct++)
#pragma unroll
    for (int j = 0; j < 4; j++)
      plw[(lg * 4 + j) * 72 + ct * 16 + lr] = (bf16_t)sc4[ct][j];
  bf16x8 pf[2];
#pragma unroll
  for (int sc = 0; sc < 2; sc++)
    pf[sc] = *reinterpret_cast<const bf16x8*>(&plw[lr * 72 + sc * 32 + lg * 8]);
#pragma unroll
  for (int ht = 0; ht < 4; ht++)
#pragma unroll
    for (int sc = 0; sc < 2; sc++) {
      bf16x8 vf = *reinterpret_cast<const bf16x8*>(
          &vl[(ht * 16 + lr) * 72 + sc * 32 + lg * 8]);
      oacc[ht] = mfma16(pf[sc], vf, oacc[ht]);
    }
}

// ---------------------------------------------------------------------------
// Causal flash attention.  grid = 512 flat blocks, block = 256 (4 waves).
// Block (p, bh): handles Q-tiles qlo=p and qhi=31-p (work-balanced: 33 tiles),
// sharing staged K/V tiles.  Blocks of one bh pinned to one XCD (f & 7).
// Next-tile K/V prefetched into registers during compute (T14).
// ---------------------------------------------------------------------------
__global__ __launch_bounds__(256) void attn_kernel(
    const bf16_t* __restrict__ qk, const bf16_t* __restrict__ vT,
    bf16_t* __restrict__ ac) {
  const int f = blockIdx.x;
  const int bh = (f & 7) + 8 * ((f >> 3) & 3);   // same bh -> same XCD
  const int p = f >> 5;                          // 0..15
  const int qlo = p, qhi = 31 - p;
  const int b = bh >> 4, h = bh & 15;
  const int tid = threadIdx.x;
  const int l = tid & 63, w = tid >> 6;
  const int lr = l & 15, lg = l >> 4;

  __shared__ __align__(16) bf16_t kl[64 * 72];
  __shared__ __align__(16) bf16_t vl[64 * 72];
  __shared__ __align__(16) bf16_t pl[4][16 * 72];
  bf16_t* plw = pl[w];

  // Q fragments for both tiles (A-operand: row=lr, k=kc*32+lg*8)
  const bf16_t* qb = qk + ((size_t)(b * 2048 + w * 16 + lr)) * 2048 + h * 64;
  bf16x8 qfl[2], qfh[2];
#pragma unroll
  for (int kc = 0; kc < 2; kc++) {
    qfl[kc] = *(const bf16x8*)(qb + (size_t)qlo * 64 * 2048 + kc * 32 + lg * 8);
    qfh[kc] = *(const bf16x8*)(qb + (size_t)qhi * 64 * 2048 + kc * 32 + lg * 8);
  }

  f32x4 oaccl[4], oacch[4];
  float ml[4], llo[4], mh[4], lhi[4];
#pragma unroll
  for (int i = 0; i < 4; i++) { oaccl[i] = (f32x4)(0.f); oacch[i] = (f32x4)(0.f); }
#pragma unroll
  for (int j = 0; j < 4; j++) { ml[j] = -1e30f; llo[j] = 0.f; mh[j] = -1e30f; lhi[j] = 0.f; }

  const int rlo = qlo * 64 + w * 16 + lg * 4;
  const int rhi = qhi * 64 + w * 16 + lg * 4;

  // staging: thread covers chunks tid and tid+256 of the 64x64 tile
  const int r0 = tid >> 3, c0 = (tid & 7) * 8;
  const bf16_t* kg = qk + ((size_t)(b * 2048)) * 2048 + 1024 + h * 64;
  const bf16_t* vg = vT + ((size_t)(bh * 64)) * 2048;

  bf16x8 kreg[2], vreg[2];
#pragma unroll
  for (int i = 0; i < 2; i++) {
    const int r = r0 + i * 32;
    kreg[i] = *(const bf16x8*)(kg + (size_t)r * 2048 + c0);
    vreg[i] = *(const bf16x8*)(vg + (size_t)r * 2048 + c0);
  }

  const int nst = qhi + 1;
  for (int st = 0; st < nst; ++st) {
    __syncthreads();   // previous tile's LDS reads complete
#pragma unroll
    for (int i = 0; i < 2; i++) {
      const int r = r0 + i * 32;
      *(bf16x8*)(&kl[r * 72 + c0]) = kreg[i];
      *(bf16x8*)(&vl[r * 72 + c0]) = vreg[i];
    }
    __syncthreads();   // tile visible to all waves
    if (st + 1 < nst) {  // prefetch next tile under compute
#pragma unroll
      for (int i = 0; i < 2; i++) {
        const int r = r0 + i * 32;
        kreg[i] = *(const bf16x8*)(kg + (size_t)((st + 1) * 64 + r) * 2048 + c0);
        vreg[i] = *(const bf16x8*)(vg + (size_t)r * 2048 + (st + 1) * 64 + c0);
      }
    }
    attn_tile(kl, vl, plw, qfh, oacch, mh, lhi, lr, lg, rhi, st * 64, st == qhi);
    if (st <= qlo)
      attn_tile(kl, vl, plw, qfl, oaccl, ml, llo, lr, lg, rlo, st * 64, st == qlo);
  }

  // epilogue: O/l -> concat-head layout [t][h*64+hs]
#pragma unroll
  for (int ht = 0; ht < 4; ht++)
#pragma unroll
    for (int j = 0; j < 4; j++) {
      const size_t tl = (size_t)(b * 2048 + rlo + j);
      ac[tl * 1024 + h * 64 + ht * 16 + lr] = (bf16_t)(oaccl[ht][j] / llo[j]);
      const size_t th = (size_t)(b * 2048 + rhi + j);
      ac[th * 1024 + h * 64 + ht * 16 + lr] = (bf16_t)(oacch[ht][j] / lhi[j]);
    }
}

// ---------------------------------------------------------------------------
extern "C" void kernel_launch(void* const* d_in, const int* in_sizes, int n_in,
                              void* d_out, int out_size, void* d_ws, size_t ws_size,
                              hipStream_t stream) {
  const float* x     = (const float*)d_in[0];
  const float* wq    = (const float*)d_in[1];
  const float* wk    = (const float*)d_in[2];
  const float* wv    = (const float*)d_in[3];
  const float* wproj = (const float*)d_in[4];
  const float* bproj = (const float*)d_in[5];
  const float* w1    = (const float*)d_in[6];
  const float* b1    = (const float*)d_in[7];
  const float* w2    = (const float*)d_in[8];
  const float* b2    = (const float*)d_in[9];
  const float* ln1g  = (const float*)d_in[10];
  const float* ln1b  = (const float*)d_in[11];
  const float* ln2g  = (const float*)d_in[12];
  const float* ln2b  = (const float*)d_in[13];
  float* out = (float*)d_out;

  char* ws = (char*)d_ws;
  const size_t MB = 1 << 20;
  bf16_t* xn  = (bf16_t*)(ws + 0);         // 8 MB   (reused as hn after LN2)
  bf16_t* wT  = (bf16_t*)(ws + 8 * MB);    // 8 MB   weight-transpose slot
  float*  hbuf= (float*)(ws + 16 * MB);    // 16 MB  residual h (f32)
  bf16_t* qkb = (bf16_t*)(ws + 32 * MB);   // 16 MB  q|k  [4096][2048]
  bf16_t* vTb = (bf16_t*)(ws + 48 * MB);   // 8 MB   v^T  [2048][2048]
  bf16_t* acb = (bf16_t*)(ws + 56 * MB);   // 8 MB   attn concat
  bf16_t* ffa = (bf16_t*)(ws + 32 * MB);   // 32 MB  ff1 act (reuses qk/vT region)
  bf16_t* hn  = xn;

  dim3 tb(32, 8);

  ln_kernel<<<4096, 256, 0, stream>>>(x, ln1g, ln1b, xn);
  transpose_cvt<<<dim3(2, 32, 16), tb, 0, stream>>>(wq, wT, 1024, 64);
  transpose_cvt<<<dim3(2, 32, 16), tb, 0, stream>>>(wk, wT + 1024 * 1024, 1024, 64);
  transpose_cvt<<<dim3(2, 32, 16), tb, 0, stream>>>(wv, wT + 2048 * 1024, 1024, 64);
  gemm_bt<0><<<dim3(24, 32), 256, 0, stream>>>(xn, wT, nullptr, nullptr, qkb, vTb,
                                               4096, 3072, 1024);
  attn_kernel<<<512, 256, 0, stream>>>(qkb, vTb, acb);
  transpose_cvt<<<dim3(32, 32, 1), tb, 0, stream>>>(wproj, wT, 1024, 1024);
  gemm_bt<1><<<dim3(8, 32), 256, 0, stream>>>(acb, wT, bproj, x, hbuf, nullptr,
                                              4096, 1024, 1024);
  ln_kernel<<<4096, 256, 0, stream>>>(hbuf, ln2g, ln2b, hn);
  transpose_cvt<<<dim3(128, 32, 1), tb, 0, stream>>>(w1, wT, 1024, 4096);
  gemm_bt<2><<<dim3(32, 32), 256, 0, stream>>>(hn, wT, b1, nullptr, ffa, nullptr,
                                               4096, 4096, 1024);
  transpose_cvt<<<dim3(32, 128, 1), tb, 0, stream>>>(w2, wT, 4096, 1024);
  gemm_bt<1><<<dim3(8, 32), 256, 0, stream>>>(ffa, wT, b2, hbuf, out, nullptr,
                                              4096, 1024, 4096);
}

// Round 4
// 412.991 us; speedup vs baseline: 1.1349x; 1.0312x over previous
//
#include <hip/hip_runtime.h>

// ---------------------------------------------------------------------------
// AttentionThinkingBlock: LN1 -> QKV -> causal attn -> proj+res -> LN2 -> MLP
// B=2, S=2048, D=1024, H=16, HS=64.  All internal matmuls in bf16 MFMA.
// Round 4: split-K for the two N=1024 GEMMs (proj, FF2) -- they had only 256
// blocks (1/CU, 10.6% occupancy, 368 TF).  Partials + reduce kernels.
// ---------------------------------------------------------------------------

typedef __bf16 bf16_t;
typedef __attribute__((ext_vector_type(8))) __bf16 bf16x8;
typedef __attribute__((ext_vector_type(4))) __bf16 bf16x4;
typedef __attribute__((ext_vector_type(4))) float f32x4;

__device__ __forceinline__ f32x4 mfma16(bf16x8 a, bf16x8 b, f32x4 c) {
  return __builtin_amdgcn_mfma_f32_16x16x32_bf16(a, b, c, 0, 0, 0);
}

__device__ __forceinline__ void gll16(const void* g, void* l) {
  __builtin_amdgcn_global_load_lds(
      (const __attribute__((address_space(1))) void*)g,
      (__attribute__((address_space(3))) void*)l, 16, 0, 0);
}

// ---------------------------------------------------------------------------
// LayerNorm (f32 in) -> bf16 out.  One block per row, D=1024.
// ---------------------------------------------------------------------------
__global__ __launch_bounds__(256) void ln_kernel(
    const float* __restrict__ x, const float* __restrict__ g,
    const float* __restrict__ be, bf16_t* __restrict__ out) {
  const int row = blockIdx.x;
  const int tid = threadIdx.x;
  const float4 v = *(reinterpret_cast<const float4*>(x + (size_t)row * 1024) + tid);
  float s1 = v.x + v.y + v.z + v.w;
  float s2 = v.x * v.x + v.y * v.y + v.z * v.z + v.w * v.w;
#pragma unroll
  for (int off = 1; off < 64; off <<= 1) {
    s1 += __shfl_xor(s1, off);
    s2 += __shfl_xor(s2, off);
  }
  __shared__ float red[8];
  const int l = tid & 63, w = tid >> 6;
  if (l == 0) { red[w] = s1; red[w + 4] = s2; }
  __syncthreads();
  s1 = red[0] + red[1] + red[2] + red[3];
  s2 = red[4] + red[5] + red[6] + red[7];
  const float mu = s1 * (1.f / 1024.f);
  const float var = s2 * (1.f / 1024.f) - mu * mu;
  const float rstd = rsqrtf(var + 1e-5f);
  const float4 gg = *(reinterpret_cast<const float4*>(g) + tid);
  const float4 bb = *(reinterpret_cast<const float4*>(be) + tid);
  bf16x4 o;
  o[0] = (bf16_t)((v.x - mu) * rstd * gg.x + bb.x);
  o[1] = (bf16_t)((v.y - mu) * rstd * gg.y + bb.y);
  o[2] = (bf16_t)((v.z - mu) * rstd * gg.z + bb.z);
  o[3] = (bf16_t)((v.w - mu) * rstd * gg.w + bb.w);
  *(reinterpret_cast<bf16x4*>(out + (size_t)row * 1024) + tid) = o;
}

// ---------------------------------------------------------------------------
// Fused: h = p0 + p1 + bproj + x  (proj split-K reduce), write hbuf f32,
// then LayerNorm(h) -> hn bf16.  One block per row.
// ---------------------------------------------------------------------------
__global__ __launch_bounds__(256) void ln2_red_kernel(
    const float* __restrict__ p, const float* __restrict__ bp,
    const float* __restrict__ x, const float* __restrict__ g,
    const float* __restrict__ be, float* __restrict__ hb,
    bf16_t* __restrict__ out) {
  const size_t PM = (size_t)4096 * 1024;
  const int row = blockIdx.x;
  const int tid = threadIdx.x;
  const size_t ro = (size_t)row * 1024;
  float4 v = *(reinterpret_cast<const float4*>(p + ro) + tid);
  const float4 v1 = *(reinterpret_cast<const float4*>(p + PM + ro) + tid);
  const float4 vb = *(reinterpret_cast<const float4*>(bp) + tid);
  const float4 vx = *(reinterpret_cast<const float4*>(x + ro) + tid);
  v.x += v1.x + vb.x + vx.x; v.y += v1.y + vb.y + vx.y;
  v.z += v1.z + vb.z + vx.z; v.w += v1.w + vb.w + vx.w;
  *(reinterpret_cast<float4*>(hb + ro) + tid) = v;
  float s1 = v.x + v.y + v.z + v.w;
  float s2 = v.x * v.x + v.y * v.y + v.z * v.z + v.w * v.w;
#pragma unroll
  for (int off = 1; off < 64; off <<= 1) {
    s1 += __shfl_xor(s1, off);
    s2 += __shfl_xor(s2, off);
  }
  __shared__ float red[8];
  const int l = tid & 63, w = tid >> 6;
  if (l == 0) { red[w] = s1; red[w + 4] = s2; }
  __syncthreads();
  s1 = red[0] + red[1] + red[2] + red[3];
  s2 = red[4] + red[5] + red[6] + red[7];
  const float mu = s1 * (1.f / 1024.f);
  const float var = s2 * (1.f / 1024.f) - mu * mu;
  const float rstd = rsqrtf(var + 1e-5f);
  const float4 gg = *(reinterpret_cast<const float4*>(g) + tid);
  const float4 bb = *(reinterpret_cast<const float4*>(be) + tid);
  bf16x4 o;
  o[0] = (bf16_t)((v.x - mu) * rstd * gg.x + bb.x);
  o[1] = (bf16_t)((v.y - mu) * rstd * gg.y + bb.y);
  o[2] = (bf16_t)((v.z - mu) * rstd * gg.z + bb.z);
  o[3] = (bf16_t)((v.w - mu) * rstd * gg.w + bb.w);
  *(reinterpret_cast<bf16x4*>(out + ro) + tid) = o;
}

// ---------------------------------------------------------------------------
// FF2 split-K reduce: out = p0+p1+p2+p3 + b2 + hbuf.  One block per row.
// ---------------------------------------------------------------------------
__global__ __launch_bounds__(256) void red4_kernel(
    const float* __restrict__ p, const float* __restrict__ b2,
    const float* __restrict__ hb, float* __restrict__ out) {
  const size_t PM = (size_t)4096 * 1024;
  const int row = blockIdx.x;
  const int tid = threadIdx.x;
  const size_t ro = (size_t)row * 1024;
  float4 v = *(reinterpret_cast<const float4*>(p + ro) + tid);
#pragma unroll
  for (int s = 1; s < 4; s++) {
    const float4 vs = *(reinterpret_cast<const float4*>(p + s * PM + ro) + tid);
    v.x += vs.x; v.y += vs.y; v.z += vs.z; v.w += vs.w;
  }
  const float4 vb = *(reinterpret_cast<const float4*>(b2) + tid);
  const float4 vh = *(reinterpret_cast<const float4*>(hb + ro) + tid);
  v.x += vb.x + vh.x; v.y += vb.y + vh.y;
  v.z += vb.z + vh.z; v.w += vb.w + vh.w;
  *(reinterpret_cast<float4*>(out + ro) + tid) = v;
}

// ---------------------------------------------------------------------------
// Batched transpose+convert: in f32 [bz][R][C] -> out bf16 [bz][C][R]
// ---------------------------------------------------------------------------
__global__ __launch_bounds__(256) void transpose_cvt(
    const float* __restrict__ in, bf16_t* __restrict__ out, int R, int C) {
  __shared__ float t[32][33];
  const int bz = blockIdx.z;
  in += (size_t)bz * R * C;
  out += (size_t)bz * R * C;
  const int c0 = blockIdx.x * 32, r0 = blockIdx.y * 32;
  const int tx = threadIdx.x, ty = threadIdx.y;
#pragma unroll
  for (int i = 0; i < 4; i++)
    t[ty + i * 8][tx] = in[(size_t)(r0 + ty + i * 8) * C + c0 + tx];
  __syncthreads();
#pragma unroll
  for (int i = 0; i < 4; i++)
    out[(size_t)(c0 + ty + i * 8) * R + r0 + tx] = (bf16_t)t[tx][ty + i * 8];
}

// ---------------------------------------------------------------------------
// GEMM C[M,N] = A[M,K] @ B^T[N,K]  (m97 structure + XCD-aware block swizzle)
// MODE 0 = QKV epilogue  MODE 1 = f32 out = acc+bias+resid  MODE 2 = relu bf16
// MODE 3 = split-K partial: blockIdx.z = chunk; writes f32 acc to
//          out0 + z*M*N (no bias/resid).
// ---------------------------------------------------------------------------
template <int MODE>
__global__ __launch_bounds__(256) void gemm_bt(
    const bf16_t* __restrict__ A, const bf16_t* __restrict__ BT,
    const float* __restrict__ bias, const float* __restrict__ resid,
    void* __restrict__ out0, void* __restrict__ out1, int M, int N, int K) {
  __shared__ __align__(16) bf16_t Al[128 * 32];
  __shared__ __align__(16) bf16_t Bl[128 * 32];
  const int tid = threadIdx.x;
  const int l = tid & 63, w = tid >> 6;
  const int wr = w >> 1, wc = w & 1;
  const int lr = l & 15, lg = l >> 4;
  const int gx = gridDim.x;
  const int nwg = gx * gridDim.y;
  int flat = blockIdx.y * gx + blockIdx.x;
  flat = (flat & 7) * (nwg >> 3) + (flat >> 3);
  const int bm = (flat / gx) * 128, bn = (flat % gx) * 128;

  int k0 = 0, nK = K >> 5;
  if constexpr (MODE == 3) {
    const int chunk = K / gridDim.z;
    k0 = blockIdx.z * chunk;
    nK = chunk >> 5;
  }

  f32x4 acc[4][4];
#pragma unroll
  for (int i = 0; i < 4; i++)
#pragma unroll
    for (int j = 0; j < 4; j++) acc[i][j] = (f32x4)(0.f);

  const char* Ag = (const char*)(A + (size_t)bm * K + k0);
  const char* Bg = (const char*)(BT + (size_t)bn * K + k0);
  const size_t rowb = (size_t)K * 2;

  for (int kt = 0; kt < nK; ++kt) {
#pragma unroll
    for (int i = 0; i < 2; i++) {
      const int s = i * 256 + tid;
      const size_t go = (size_t)(s >> 2) * rowb + (size_t)(kt * 64 + (s & 3) * 16);
      gll16(Ag + go, (char*)Al + (i * 256 + w * 64) * 16);
      gll16(Bg + go, (char*)Bl + (i * 256 + w * 64) * 16);
    }
    __syncthreads();
    bf16x8 af[4], bfr[4];
#pragma unroll
    for (int mi = 0; mi < 4; mi++)
      af[mi] = *reinterpret_cast<const bf16x8*>(Al + (wr * 64 + mi * 16 + lr) * 32 + lg * 8);
#pragma unroll
    for (int ni = 0; ni < 4; ni++)
      bfr[ni] = *reinterpret_cast<const bf16x8*>(Bl + (wc * 64 + ni * 16 + lr) * 32 + lg * 8);
#pragma unroll
    for (int mi = 0; mi < 4; mi++)
#pragma unroll
      for (int ni = 0; ni < 4; ni++)
        acc[mi][ni] = mfma16(af[mi], bfr[ni], acc[mi][ni]);
    __syncthreads();
  }

#pragma unroll
  for (int mi = 0; mi < 4; mi++) {
    const int r = bm + wr * 64 + mi * 16 + lg * 4;
#pragma unroll
    for (int ni = 0; ni < 4; ni++) {
      const int c = bn + wc * 64 + ni * 16 + lr;
      f32x4 v = acc[mi][ni];
      if constexpr (MODE == 1) {
        const float bb = bias[c];
        float* o = (float*)out0;
#pragma unroll
        for (int j = 0; j < 4; j++)
          o[(size_t)(r + j) * N + c] = v[j] + bb + resid[(size_t)(r + j) * N + c];
      } else if constexpr (MODE == 2) {
        const float bb = bias[c];
        bf16_t* o = (bf16_t*)out0;
#pragma unroll
        for (int j = 0; j < 4; j++)
          o[(size_t)(r + j) * N + c] = (bf16_t)fmaxf(v[j] + bb, 0.f);
      } else if constexpr (MODE == 3) {
        float* o = (float*)out0 + (size_t)blockIdx.z * M * N;
#pragma unroll
        for (int j = 0; j < 4; j++)
          o[(size_t)(r + j) * N + c] = v[j];
      } else {
        if (c < 2048) {
          bf16_t* o = (bf16_t*)out0;
#pragma unroll
          for (int j = 0; j < 4; j++)
            o[(size_t)(r + j) * 2048 + c] = (bf16_t)v[j];
        } else {
          const int nn = c - 2048;
          const int bI = r >> 11, tl = r & 2047;
          bf16x4 pk;
#pragma unroll
          for (int j = 0; j < 4; j++) pk[j] = (bf16_t)v[j];
          *reinterpret_cast<bf16x4*>((bf16_t*)out1 +
              ((size_t)(bI * 1024 + nn)) * 2048 + tl) = pk;
        }
      }
    }
  }
}

// ---------------------------------------------------------------------------
// One K-tile of flash attention for one wave's 16 Q-rows.
// ---------------------------------------------------------------------------
__device__ __forceinline__ void attn_tile(
    const bf16_t* __restrict__ kl, const bf16_t* __restrict__ vl,
    bf16_t* __restrict__ plw, const bf16x8* qf, f32x4* oacc,
    float* mrow, float* lrow, const int lr, const int lg,
    const int rbase, const int cbase, const bool diag) {
  f32x4 sc4[4];
#pragma unroll
  for (int ct = 0; ct < 4; ct++) sc4[ct] = (f32x4)(0.f);
#pragma unroll
  for (int ct = 0; ct < 4; ct++)
#pragma unroll
    for (int kc = 0; kc < 2; kc++) {
      bf16x8 kf = *reinterpret_cast<const bf16x8*>(
          &kl[(ct * 16 + lr) * 72 + kc * 32 + lg * 8]);
      sc4[ct] = mfma16(qf[kc], kf, sc4[ct]);
    }
#pragma unroll
  for (int ct = 0; ct < 4; ct++)
#pragma unroll
    for (int j = 0; j < 4; j++) {
      float sv = sc4[ct][j] * 0.125f;
      if (diag && (cbase + ct * 16 + lr > rbase + j)) sv = -1e30f;
      sc4[ct][j] = sv;
    }
  float rmax[4];
#pragma unroll
  for (int j = 0; j < 4; j++)
    rmax[j] = fmaxf(fmaxf(sc4[0][j], sc4[1][j]), fmaxf(sc4[2][j], sc4[3][j]));
#pragma unroll
  for (int off = 1; off < 16; off <<= 1)
#pragma unroll
    for (int j = 0; j < 4; j++) rmax[j] = fmaxf(rmax[j], __shfl_xor(rmax[j], off));
  float fac[4];
#pragma unroll
  for (int j = 0; j < 4; j++) {
    const float mn = fmaxf(mrow[j], rmax[j]);
    fac[j] = __expf(mrow[j] - mn);
    mrow[j] = mn;
  }
  float rsum[4] = {0.f, 0.f, 0.f, 0.f};
#pragma unroll
  for (int ct = 0; ct < 4; ct++)
#pragma unroll
    for (int j = 0; j < 4; j++) {
      const float pv = __expf(sc4[ct][j] - mrow[j]);
      sc4[ct][j] = pv;
      rsum[j] += pv;
    }
#pragma unroll
  for (int off = 1; off < 16; off <<= 1)
#pragma unroll
    for (int j = 0; j < 4; j++) rsum[j] += __shfl_xor(rsum[j], off);
#pragma unroll
  for (int j = 0; j < 4; j++) lrow[j] = lrow[j] * fac[j] + rsum[j];
#pragma unroll
  for (int ht = 0; ht < 4; ht++)
#pragma unroll
    for (int j = 0; j < 4; j++) oacc[ht][j] *= fac[j];
#pragma unroll
  for (int ct = 0; ct < 4; ct++)
#pragma unroll
    for (int j = 0; j < 4; j++)
      plw[(lg * 4 + j) * 72 + ct * 16 + lr] = (bf16_t)sc4[ct][j];
  bf16x8 pf[2];
#pragma unroll
  for (int sc = 0; sc < 2; sc++)
    pf[sc] = *reinterpret_cast<const bf16x8*>(&plw[lr * 72 + sc * 32 + lg * 8]);
#pragma unroll
  for (int ht = 0; ht < 4; ht++)
#pragma unroll
    for (int sc = 0; sc < 2; sc++) {
      bf16x8 vf = *reinterpret_cast<const bf16x8*>(
          &vl[(ht * 16 + lr) * 72 + sc * 32 + lg * 8]);
      oacc[ht] = mfma16(pf[sc], vf, oacc[ht]);
    }
}

// ---------------------------------------------------------------------------
// Causal flash attention.  Paired Q-tiles (p, 31-p), XCD-pinned bh, reg prefetch.
// ---------------------------------------------------------------------------
__global__ __launch_bounds__(256) void attn_kernel(
    const bf16_t* __restrict__ qk, const bf16_t* __restrict__ vT,
    bf16_t* __restrict__ ac) {
  const int f = blockIdx.x;
  const int bh = (f & 7) + 8 * ((f >> 3) & 3);
  const int p = f >> 5;
  const int qlo = p, qhi = 31 - p;
  const int b = bh >> 4, h = bh & 15;
  const int tid = threadIdx.x;
  const int l = tid & 63, w = tid >> 6;
  const int lr = l & 15, lg = l >> 4;

  __shared__ __align__(16) bf16_t kl[64 * 72];
  __shared__ __align__(16) bf16_t vl[64 * 72];
  __shared__ __align__(16) bf16_t pl[4][16 * 72];
  bf16_t* plw = pl[w];

  const bf16_t* qb = qk + ((size_t)(b * 2048 + w * 16 + lr)) * 2048 + h * 64;
  bf16x8 qfl[2], qfh[2];
#pragma unroll
  for (int kc = 0; kc < 2; kc++) {
    qfl[kc] = *(const bf16x8*)(qb + (size_t)qlo * 64 * 2048 + kc * 32 + lg * 8);
    qfh[kc] = *(const bf16x8*)(qb + (size_t)qhi * 64 * 2048 + kc * 32 + lg * 8);
  }

  f32x4 oaccl[4], oacch[4];
  float ml[4], llo[4], mh[4], lhi[4];
#pragma unroll
  for (int i = 0; i < 4; i++) { oaccl[i] = (f32x4)(0.f); oacch[i] = (f32x4)(0.f); }
#pragma unroll
  for (int j = 0; j < 4; j++) { ml[j] = -1e30f; llo[j] = 0.f; mh[j] = -1e30f; lhi[j] = 0.f; }

  const int rlo = qlo * 64 + w * 16 + lg * 4;
  const int rhi = qhi * 64 + w * 16 + lg * 4;

  const int r0 = tid >> 3, c0 = (tid & 7) * 8;
  const bf16_t* kg = qk + ((size_t)(b * 2048)) * 2048 + 1024 + h * 64;
  const bf16_t* vg = vT + ((size_t)(bh * 64)) * 2048;

  bf16x8 kreg[2], vreg[2];
#pragma unroll
  for (int i = 0; i < 2; i++) {
    const int r = r0 + i * 32;
    kreg[i] = *(const bf16x8*)(kg + (size_t)r * 2048 + c0);
    vreg[i] = *(const bf16x8*)(vg + (size_t)r * 2048 + c0);
  }

  const int nst = qhi + 1;
  for (int st = 0; st < nst; ++st) {
    __syncthreads();
#pragma unroll
    for (int i = 0; i < 2; i++) {
      const int r = r0 + i * 32;
      *(bf16x8*)(&kl[r * 72 + c0]) = kreg[i];
      *(bf16x8*)(&vl[r * 72 + c0]) = vreg[i];
    }
    __syncthreads();
    if (st + 1 < nst) {
#pragma unroll
      for (int i = 0; i < 2; i++) {
        const int r = r0 + i * 32;
        kreg[i] = *(const bf16x8*)(kg + (size_t)((st + 1) * 64 + r) * 2048 + c0);
        vreg[i] = *(const bf16x8*)(vg + (size_t)r * 2048 + (st + 1) * 64 + c0);
      }
    }
    attn_tile(kl, vl, plw, qfh, oacch, mh, lhi, lr, lg, rhi, st * 64, st == qhi);
    if (st <= qlo)
      attn_tile(kl, vl, plw, qfl, oaccl, ml, llo, lr, lg, rlo, st * 64, st == qlo);
  }

#pragma unroll
  for (int ht = 0; ht < 4; ht++)
#pragma unroll
    for (int j = 0; j < 4; j++) {
      const size_t tl = (size_t)(b * 2048 + rlo + j);
      ac[tl * 1024 + h * 64 + ht * 16 + lr] = (bf16_t)(oaccl[ht][j] / llo[j]);
      const size_t th = (size_t)(b * 2048 + rhi + j);
      ac[th * 1024 + h * 64 + ht * 16 + lr] = (bf16_t)(oacch[ht][j] / lhi[j]);
    }
}

// ---------------------------------------------------------------------------
extern "C" void kernel_launch(void* const* d_in, const int* in_sizes, int n_in,
                              void* d_out, int out_size, void* d_ws, size_t ws_size,
                              hipStream_t stream) {
  const float* x     = (const float*)d_in[0];
  const float* wq    = (const float*)d_in[1];
  const float* wk    = (const float*)d_in[2];
  const float* wv    = (const float*)d_in[3];
  const float* wproj = (const float*)d_in[4];
  const float* bproj = (const float*)d_in[5];
  const float* w1    = (const float*)d_in[6];
  const float* b1    = (const float*)d_in[7];
  const float* w2    = (const float*)d_in[8];
  const float* b2    = (const float*)d_in[9];
  const float* ln1g  = (const float*)d_in[10];
  const float* ln1b  = (const float*)d_in[11];
  const float* ln2g  = (const float*)d_in[12];
  const float* ln2b  = (const float*)d_in[13];
  float* out = (float*)d_out;

  char* ws = (char*)d_ws;
  const size_t MB = 1 << 20;
  bf16_t* xn  = (bf16_t*)(ws + 0);         // 8 MB  (reused as hn after LN2)
  bf16_t* wT  = (bf16_t*)(ws + 8 * MB);    // 8 MB  weight-transpose slot
  float*  hbuf= (float*)(ws + 16 * MB);    // 16 MB residual h (f32)
  bf16_t* qkb = (bf16_t*)(ws + 32 * MB);   // 16 MB q|k  [4096][2048]
  bf16_t* vTb = (bf16_t*)(ws + 48 * MB);   // 8 MB  v^T
  bf16_t* acb = (bf16_t*)(ws + 56 * MB);   // 8 MB  attn concat
  bf16_t* ffa = (bf16_t*)(ws + 32 * MB);   // 32 MB ff1 act (reuses qk/vT/ac)
  float*  part= (float*)(ws + 64 * MB);    // 64 MB split-K partials (big path)
  bf16_t* hn  = xn;

  const bool big = ws_size >= 128 * MB;
  dim3 tb(32, 8);

  ln_kernel<<<4096, 256, 0, stream>>>(x, ln1g, ln1b, xn);
  transpose_cvt<<<dim3(2, 32, 16), tb, 0, stream>>>(wq, wT, 1024, 64);
  transpose_cvt<<<dim3(2, 32, 16), tb, 0, stream>>>(wk, wT + 1024 * 1024, 1024, 64);
  transpose_cvt<<<dim3(2, 32, 16), tb, 0, stream>>>(wv, wT + 2048 * 1024, 1024, 64);
  gemm_bt<0><<<dim3(24, 32), 256, 0, stream>>>(xn, wT, nullptr, nullptr, qkb, vTb,
                                               4096, 3072, 1024);
  attn_kernel<<<512, 256, 0, stream>>>(qkb, vTb, acb);
  transpose_cvt<<<dim3(32, 32, 1), tb, 0, stream>>>(wproj, wT, 1024, 1024);
  if (big) {
    // proj split-K=2 -> partials; reduce fused into LN2
    gemm_bt<3><<<dim3(8, 32, 2), 256, 0, stream>>>(acb, wT, nullptr, nullptr,
                                                   part, nullptr, 4096, 1024, 1024);
    ln2_red_kernel<<<4096, 256, 0, stream>>>(part, bproj, x, ln2g, ln2b, hbuf, hn);
  } else {
    gemm_bt<1><<<dim3(8, 32), 256, 0, stream>>>(acb, wT, bproj, x, hbuf, nullptr,
                                                4096, 1024, 1024);
    ln_kernel<<<4096, 256, 0, stream>>>(hbuf, ln2g, ln2b, hn);
  }
  transpose_cvt<<<dim3(128, 32, 1), tb, 0, stream>>>(w1, wT, 1024, 4096);
  gemm_bt<2><<<dim3(32, 32), 256, 0, stream>>>(hn, wT, b1, nullptr, ffa, nullptr,
                                               4096, 4096, 1024);
  transpose_cvt<<<dim3(32, 128, 1), tb, 0, stream>>>(w2, wT, 4096, 1024);
  if (big) {
    // FF2 split-K=4 -> partials; reduce + bias + residual -> out
    gemm_bt<3><<<dim3(8, 32, 4), 256, 0, stream>>>(ffa, wT, nullptr, nullptr,
                                                   part, nullptr, 4096, 1024, 4096);
    red4_kernel<<<4096, 256, 0, stream>>>(part, b2, hbuf, out);
  } else {
    gemm_bt<1><<<dim3(8, 32), 256, 0, stream>>>(ffa, wT, b2, hbuf, out, nullptr,
                                                4096, 1024, 4096);
  }
}